// Round 3
// baseline (669.969 us; speedup 1.0000x reference)
//
#include <hip/hip_runtime.h>
#include <math.h>

// Batched log-domain Sinkhorn, 256 x 512 x 512 fp32, MAX_ITER=10, TAU=0.05.
// Potentials formulation: log_s = L0 - u_i - v_j with
//   u_i = LSE_j(L0 - v_j)  (even iters),  v_j = LSE_i(L0 - u_i)  (odd iters).
// Run entirely in base-2 log domain: w = s * (1/TAU) * log2(e).

#if __has_builtin(__builtin_amdgcn_exp2f)
__device__ __forceinline__ float fexp2(float x) { return __builtin_amdgcn_exp2f(x); }
#else
__device__ __forceinline__ float fexp2(float x) { return exp2f(x); }
#endif
#if __has_builtin(__builtin_amdgcn_logf)
__device__ __forceinline__ float flog2(float x) { return __builtin_amdgcn_logf(x); }
#else
__device__ __forceinline__ float flog2(float x) { return log2f(x); }
#endif

constexpr int N = 512;       // matrix dim
constexpr int NB = 256;      // batch
constexpr int PASSES = 5;    // 10 iters = 5 fused (row,col) pairs
constexpr int NWAVE = 16;    // 1024 threads
constexpr float SCALE = 28.85390081777927f; // (1/0.05) * log2(e)

__global__ __launch_bounds__(1024)
void sinkhorn_fused(const float* __restrict__ S, float* __restrict__ O)
{
    __shared__ float u2[N];          // row potentials (log2 domain)
    __shared__ float v2[N];          // col potentials (log2 domain)
    __shared__ float pm[NWAVE][N];   // per-wave col partial max
    __shared__ float ps[NWAVE][N];   // per-wave col partial sum

    const int tid  = threadIdx.x;
    const int wave = tid >> 6;
    const int lane = tid & 63;
    const size_t base = (size_t)blockIdx.x * N * N;
    const float* __restrict__ Sb = S + base;
    float* __restrict__ Ob = O + base;

    if (tid < N) v2[tid] = 0.0f;
    __syncthreads();

    // lane owns columns c0..c0+3 and c1..c1+3 (two coalesced 1KiB segments/row)
    const int c0 = lane * 4;
    const int c1 = 256 + lane * 4;
    const int r0 = wave * 32;        // wave owns rows [r0, r0+32)

    for (int pass = 0; pass < PASSES; ++pass) {
        // v for my columns: loop-invariant within a pass
        float4 va = *(const float4*)&v2[c0];
        float4 vb = *(const float4*)&v2[c1];
        float vv[8] = {va.x, va.y, va.z, va.w, vb.x, vb.y, vb.z, vb.w};

        float cm[8], cs[8];          // online col accumulators (m, s)
        #pragma unroll
        for (int k = 0; k < 8; ++k) { cm[k] = -INFINITY; cs[k] = 0.0f; }

        #pragma unroll 2
        for (int r = r0; r < r0 + 32; ++r) {
            float4 a = *(const float4*)&Sb[(size_t)r * N + c0];
            float4 b = *(const float4*)&Sb[(size_t)r * N + c1];
            float w[8] = {a.x, a.y, a.z, a.w, b.x, b.y, b.z, b.w};
            float x[8];
            float mx = -INFINITY;
            #pragma unroll
            for (int k = 0; k < 8; ++k) {
                w[k] *= SCALE;
                x[k] = w[k] - vv[k];
                mx = fmaxf(mx, x[k]);
            }
            // wave-reduce max (butterfly -> all lanes)
            #pragma unroll
            for (int off = 32; off >= 1; off >>= 1)
                mx = fmaxf(mx, __shfl_xor(mx, off));
            float sum = 0.0f;
            #pragma unroll
            for (int k = 0; k < 8; ++k) sum += fexp2(x[k] - mx);
            #pragma unroll
            for (int off = 32; off >= 1; off >>= 1)
                sum += __shfl_xor(sum, off);
            const float ui = mx + flog2(sum);   // u_i, uniform across lanes
            if (lane == 0) u2[r] = ui;
            // fold this row into online column partials: t = w - u_i
            #pragma unroll
            for (int k = 0; k < 8; ++k) {
                float t  = w[k] - ui;
                float mn = fmaxf(cm[k], t);
                cs[k] = cs[k] * fexp2(cm[k] - mn) + fexp2(t - mn);
                cm[k] = mn;
            }
        }

        // publish per-wave column partials
        *(float4*)&pm[wave][c0] = make_float4(cm[0], cm[1], cm[2], cm[3]);
        *(float4*)&pm[wave][c1] = make_float4(cm[4], cm[5], cm[6], cm[7]);
        *(float4*)&ps[wave][c0] = make_float4(cs[0], cs[1], cs[2], cs[3]);
        *(float4*)&ps[wave][c1] = make_float4(cs[4], cs[5], cs[6], cs[7]);
        __syncthreads();

        // merge 16 partials per column -> v2
        if (tid < N) {
            float M = -INFINITY;
            #pragma unroll
            for (int p = 0; p < NWAVE; ++p) M = fmaxf(M, pm[p][tid]);
            float Ss = 0.0f;
            #pragma unroll
            for (int p = 0; p < NWAVE; ++p) Ss += ps[p][tid] * fexp2(pm[p][tid] - M);
            v2[tid] = M + flog2(Ss);
        }
        __syncthreads();
    }

    // final pass: out = 2^(w - u_i - v_j)
    {
        float4 va = *(const float4*)&v2[c0];
        float4 vb = *(const float4*)&v2[c1];
        float vv[8] = {va.x, va.y, va.z, va.w, vb.x, vb.y, vb.z, vb.w};
        for (int r = r0; r < r0 + 32; ++r) {
            float4 a = *(const float4*)&Sb[(size_t)r * N + c0];
            float4 b = *(const float4*)&Sb[(size_t)r * N + c1];
            const float ui = u2[r];
            float w[8] = {a.x, a.y, a.z, a.w, b.x, b.y, b.z, b.w};
            float o[8];
            #pragma unroll
            for (int k = 0; k < 8; ++k)
                o[k] = fexp2(w[k] * SCALE - ui - vv[k]);
            *(float4*)&Ob[(size_t)r * N + c0] = make_float4(o[0], o[1], o[2], o[3]);
            *(float4*)&Ob[(size_t)r * N + c1] = make_float4(o[4], o[5], o[6], o[7]);
        }
    }
}

extern "C" void kernel_launch(void* const* d_in, const int* in_sizes, int n_in,
                              void* d_out, int out_size, void* d_ws, size_t ws_size,
                              hipStream_t stream)
{
    const float* S = (const float*)d_in[0];
    float* O = (float*)d_out;
    sinkhorn_fused<<<NB, 1024, 0, stream>>>(S, O);
}